// Round 1
// baseline (1144.971 us; speedup 1.0000x reference)
//
#include <hip/hip_runtime.h>

typedef unsigned short u16;
typedef unsigned int u32;
typedef __bf16 bf16x8 __attribute__((ext_vector_type(8)));
typedef float f32x4 __attribute__((ext_vector_type(4)));
typedef u16 u16x4 __attribute__((ext_vector_type(4)));
typedef float f4v __attribute__((ext_vector_type(4)));

#define NB   512
#define CCH  256
#define HW   196
#define LROW 40          // LDS row stride in bf16 elems (80 B -> conflict-free)

__device__ inline u16 f2bf(float f) {
    u32 u = __float_as_uint(f);
    u32 r = (u + 0x7FFFu + ((u >> 16) & 1u)) >> 16;
    return (u16)r;
}

// ---------------- weight convert / reorder ----------------
// 3x3: W[co][ci][r][s] f32 -> w3[wset][rs][co][ci] bf16 ; 1x1: linear convert
__global__ void wconv_kernel(const float* __restrict__ Wc3, const float* __restrict__ Wt3,
                             const float* __restrict__ Wf3, const float* __restrict__ Wc1,
                             const float* __restrict__ Wt1, const float* __restrict__ Wf1,
                             u16* __restrict__ w3, u16* __restrict__ w1o)
{
    int bid = blockIdx.x, tid = threadIdx.x;
    if (bid < 768) {
        int wsel = bid >> 8;
        int co = bid & 255;
        const float* src = wsel == 0 ? Wc3 : (wsel == 1 ? Wt3 : Wf3);
#pragma unroll
        for (int rs = 0; rs < 9; ++rs) {
            float v = src[(co * 256 + tid) * 9 + rs];
            w3[wsel * 589824 + (rs * 256 + co) * 256 + tid] = f2bf(v);
        }
    } else {
        int k = (bid - 768) * 256 + tid;      // unit of 4 elems, [0, 49152)
        int wsel = k >> 14;
        int rem = k & 16383;
        const float* src = wsel == 0 ? Wc1 : (wsel == 1 ? Wt1 : Wf1);
        f4v v = *(const f4v*)(src + rem * 4);
        u16x4 o = { f2bf(v.x), f2bf(v.y), f2bf(v.z), f2bf(v.w) };
        *(u16x4*)(w1o + wsel * 65536 + rem * 4) = o;
    }
}

// ---------------- box overlap mask ----------------
__global__ void mask_kernel(const float* __restrict__ boxes, int* __restrict__ counts,
                            int* __restrict__ members)
{
    int i = blockIdx.x;
    int ln = threadIdx.x;   // 64 threads
    __shared__ int cnt;
    if (ln == 0) cnt = 0;
    __syncthreads();
    float xi0 = boxes[i * 4 + 0], yi0 = boxes[i * 4 + 1];
    float xi1 = boxes[i * 4 + 2], yi1 = boxes[i * 4 + 3];
    for (int j = ln; j < NB; j += 64) {
        float xj0 = boxes[j * 4 + 0], yj0 = boxes[j * 4 + 1];
        float xj1 = boxes[j * 4 + 2], yj1 = boxes[j * 4 + 3];
        float areaj = (xj1 - xj0) * (yj1 - yj0);
        float lx = fmaxf(xi0, xj0), ly = fmaxf(yi0, yj0);
        float rx = fminf(xi1, xj1), ry = fminf(yi1, yj1);
        float w = fmaxf(rx - lx, 0.f), h = fmaxf(ry - ly, 0.f);
        float inter = w * h;
        if (inter / areaj > 0.9f) {
            int p = atomicAdd(&cnt, 1);
            members[i * NB + p] = j;
        }
    }
    __syncthreads();
    if (ln == 0) counts[i] = cnt;
}

// ---------------- branch input (bf16) ----------------
// bin[i] = classes[i]!=0 ? x[i] : (counts[i]>1 ? avg(members) : x[i])
__global__ void bin_kernel(const float* __restrict__ x, const int* __restrict__ classes,
                           const int* __restrict__ counts, const int* __restrict__ members,
                           u16* __restrict__ bin)
{
    const int s = blockIdx.x, tid = threadIdx.x;
    const int base = s * (CCH * HW);
    const int cnt = counts[s];
    if (classes[s] != 0 || cnt <= 1) {
        for (int u = tid; u < (CCH * HW) / 4; u += 256) {
            f4v v = *(const f4v*)(x + base + u * 4);
            u16x4 o = { f2bf(v.x), f2bf(v.y), f2bf(v.z), f2bf(v.w) };
            *(u16x4*)(bin + base + u * 4) = o;
        }
    } else {
        __shared__ int mem[NB];
        for (int u = tid; u < cnt; u += 256) mem[u] = members[s * NB + u];
        __syncthreads();
        const float inv = 1.f / (float)cnt;
        for (int u = tid; u < (CCH * HW) / 4; u += 256) {
            float a0 = 0.f, a1 = 0.f, a2 = 0.f, a3 = 0.f;
            for (int k = 0; k < cnt; ++k) {
                const f4v v = *(const f4v*)(x + mem[k] * (CCH * HW) + u * 4);
                a0 += v.x; a1 += v.y; a2 += v.z; a3 += v.w;
            }
            u16x4 o = { f2bf(a0 * inv), f2bf(a1 * inv), f2bf(a2 * inv), f2bf(a3 * inv) };
            *(u16x4*)(bin + base + u * 4) = o;
        }
    }
}

// ---------------- conv3x3 (pad 1) via MFMA implicit GEMM ----------------
// grid 1024: s = bid>>1, co-group = bid&1 (128 co). block 256 = 4 waves,
// wave = 32 co x 208 px (13 tiles of 16). K = 8 chunks of 32 ci x 9 taps.
__global__ __launch_bounds__(256, 2) void conv3x3_kernel(
    const u16* __restrict__ in, u16* __restrict__ out,
    const u16* __restrict__ w0, const u16* __restrict__ w1,
    const int* __restrict__ classes, int useClass)
{
    __shared__ u16 lds[197 * LROW];
    const int tid = threadIdx.x;
    const int bid = blockIdx.x;
    const int s = bid >> 1;
    const int cg = bid & 1;
    const int wv = tid >> 6;
    const int ln = tid & 63;
    const int q = ln >> 4;
    const int l15 = ln & 15;
    const int cow = cg * 128 + wv * 32;

    const u16* wsel = w0;
    if (useClass && classes[s] == 0) wsel = w1;

    if (tid < 20) ((u32*)lds)[196 * (LROW / 2) + tid] = 0u;   // zero halo row

    int baddr[13], vbits[13];
#pragma unroll
    for (int t = 0; t < 13; ++t) {
        int px = t * 16 + l15;
        int y = px / 14;
        int x = px - y * 14;
        baddr[t] = px * LROW + q * 8;
        int vb = 0;
#pragma unroll
        for (int rs = 0; rs < 9; ++rs) {
            int iy = y + rs / 3 - 1;
            int ix = x + rs % 3 - 1;
            if (iy >= 0 && iy < 14 && ix >= 0 && ix < 14) vb |= 1 << rs;
        }
        vbits[t] = vb;
    }

    f32x4 acc[2][13];
#pragma unroll
    for (int a = 0; a < 2; ++a)
#pragma unroll
        for (int t = 0; t < 13; ++t) acc[a][t] = (f32x4){0.f, 0.f, 0.f, 0.f};

    const u16* inS = in + s * (CCH * HW);

    for (int cc = 0; cc < 8; ++cc) {
        __syncthreads();
        for (int u = tid; u < 1568; u += 256) {          // 32 ci x 49 quad-px
            int ci = u / 49;
            int p4 = (u - ci * 49) * 4;
            u16x4 v = *(const u16x4*)(inS + (cc * 32 + ci) * HW + p4);
            lds[(p4 + 0) * LROW + ci] = v.x;
            lds[(p4 + 1) * LROW + ci] = v.y;
            lds[(p4 + 2) * LROW + ci] = v.z;
            lds[(p4 + 3) * LROW + ci] = v.w;
        }
        __syncthreads();

#pragma unroll
        for (int rs = 0; rs < 9; ++rs) {
            const int d = (rs / 3 - 1) * 14 + (rs % 3 - 1);
            bf16x8 a0 = *(const bf16x8*)(wsel + ((rs * 256 + cow + l15) * 256 + cc * 32 + q * 8));
            bf16x8 a1 = *(const bf16x8*)(wsel + ((rs * 256 + cow + 16 + l15) * 256 + cc * 32 + q * 8));
#pragma unroll
            for (int t = 0; t < 13; ++t) {
                int addr = ((vbits[t] >> rs) & 1) ? (baddr[t] + d * LROW)
                                                  : (196 * LROW + q * 8);
                bf16x8 b = *(const bf16x8*)(lds + addr);
                acc[0][t] = __builtin_amdgcn_mfma_f32_16x16x32_bf16(a0, b, acc[0][t], 0, 0, 0);
                acc[1][t] = __builtin_amdgcn_mfma_f32_16x16x32_bf16(a1, b, acc[1][t], 0, 0, 0);
            }
        }
    }

#pragma unroll
    for (int sub = 0; sub < 2; ++sub)
#pragma unroll
        for (int t = 0; t < 13; ++t) {
            int px = t * 16 + l15;
            if (px < HW) {
#pragma unroll
                for (int rg = 0; rg < 4; ++rg) {
                    int co = cow + sub * 16 + q * 4 + rg;
                    out[(s * CCH + co) * HW + px] = f2bf(acc[sub][t][rg]);
                }
            }
        }
}

// ---------------- conv1x1 via MFMA, fused epilogues ----------------
// MODE 0: out_bf16 = acc + x + gc (fuse).  MODE 1: out_f32 = relu(BN(acc)).
template <int MODE>
__global__ __launch_bounds__(256, 2) void conv1x1_kernel(
    const u16* __restrict__ in, const u16* __restrict__ w0, const u16* __restrict__ w1,
    const int* __restrict__ classes, int useClass,
    const float* __restrict__ xin, const float* __restrict__ gcin,
    const float* __restrict__ gamma, const float* __restrict__ beta,
    const float* __restrict__ mean, const float* __restrict__ var,
    void* __restrict__ outv)
{
    __shared__ u16 lds[197 * LROW];
    const int tid = threadIdx.x;
    const int bid = blockIdx.x;
    const int s = bid >> 1;
    const int cg = bid & 1;
    const int wv = tid >> 6;
    const int ln = tid & 63;
    const int q = ln >> 4;
    const int l15 = ln & 15;
    const int cow = cg * 128 + wv * 32;

    const u16* wsel = w0;
    if (useClass && classes[s] == 0) wsel = w1;

    if (tid < 20) ((u32*)lds)[196 * (LROW / 2) + tid] = 0u;

    int baddr[13];
#pragma unroll
    for (int t = 0; t < 13; ++t) {
        int px = t * 16 + l15;
        baddr[t] = (px < HW ? px : 196) * LROW + q * 8;
    }

    f32x4 acc[2][13];
#pragma unroll
    for (int a = 0; a < 2; ++a)
#pragma unroll
        for (int t = 0; t < 13; ++t) acc[a][t] = (f32x4){0.f, 0.f, 0.f, 0.f};

    const u16* inS = in + s * (CCH * HW);

    for (int cc = 0; cc < 8; ++cc) {
        __syncthreads();
        for (int u = tid; u < 1568; u += 256) {
            int ci = u / 49;
            int p4 = (u - ci * 49) * 4;
            u16x4 v = *(const u16x4*)(inS + (cc * 32 + ci) * HW + p4);
            lds[(p4 + 0) * LROW + ci] = v.x;
            lds[(p4 + 1) * LROW + ci] = v.y;
            lds[(p4 + 2) * LROW + ci] = v.z;
            lds[(p4 + 3) * LROW + ci] = v.w;
        }
        __syncthreads();

        bf16x8 a0 = *(const bf16x8*)(wsel + ((cow + l15) * 256 + cc * 32 + q * 8));
        bf16x8 a1 = *(const bf16x8*)(wsel + ((cow + 16 + l15) * 256 + cc * 32 + q * 8));
#pragma unroll
        for (int t = 0; t < 13; ++t) {
            bf16x8 b = *(const bf16x8*)(lds + baddr[t]);
            acc[0][t] = __builtin_amdgcn_mfma_f32_16x16x32_bf16(a0, b, acc[0][t], 0, 0, 0);
            acc[1][t] = __builtin_amdgcn_mfma_f32_16x16x32_bf16(a1, b, acc[1][t], 0, 0, 0);
        }
    }

    if (MODE == 0) {
        u16* outb = (u16*)outv;
#pragma unroll
        for (int sub = 0; sub < 2; ++sub)
#pragma unroll
            for (int t = 0; t < 13; ++t) {
                int px = t * 16 + l15;
                if (px < HW) {
#pragma unroll
                    for (int rg = 0; rg < 4; ++rg) {
                        int co = cow + sub * 16 + q * 4 + rg;
                        int idx = (s * CCH + co) * HW + px;
                        float v = acc[sub][t][rg] + xin[idx] + gcin[idx];
                        outb[idx] = f2bf(v);
                    }
                }
            }
    } else {
        float* outf = (float*)outv;
        float scl[2][4], mn[2][4], bt[2][4];
#pragma unroll
        for (int sub = 0; sub < 2; ++sub)
#pragma unroll
            for (int rg = 0; rg < 4; ++rg) {
                int c = cow + sub * 16 + q * 4 + rg;
                scl[sub][rg] = gamma[c] * rsqrtf(var[c] + 1e-5f);
                mn[sub][rg] = mean[c];
                bt[sub][rg] = beta[c];
            }
#pragma unroll
        for (int sub = 0; sub < 2; ++sub)
#pragma unroll
            for (int t = 0; t < 13; ++t) {
                int px = t * 16 + l15;
                if (px < HW) {
#pragma unroll
                    for (int rg = 0; rg < 4; ++rg) {
                        int co = cow + sub * 16 + q * 4 + rg;
                        float v = (acc[sub][t][rg] - mn[sub][rg]) * scl[sub][rg] + bt[sub][rg];
                        outf[(s * CCH + co) * HW + px] = fmaxf(v, 0.f);
                    }
                }
            }
    }
}

// ---------------- launch ----------------
extern "C" void kernel_launch(void* const* d_in, const int* in_sizes, int n_in,
                              void* d_out, int out_size, void* d_ws, size_t ws_size,
                              hipStream_t stream)
{
    const float* x    = (const float*)d_in[0];
    const float* gc   = (const float*)d_in[1];
    const float* boxes= (const float*)d_in[2];
    const int*   cls  = (const int*)d_in[3];
    const float* Wc3  = (const float*)d_in[4];
    const float* Wc1  = (const float*)d_in[5];
    const float* Wt3  = (const float*)d_in[6];
    const float* Wt1  = (const float*)d_in[7];
    const float* Wf3  = (const float*)d_in[8];
    const float* Wf1  = (const float*)d_in[9];
    const float* gam  = (const float*)d_in[10];
    const float* bet  = (const float*)d_in[11];
    const float* mea  = (const float*)d_in[12];
    const float* var  = (const float*)d_in[13];
    float* out = (float*)d_out;
    char* ws = (char*)d_ws;

    u16* w3      = (u16*)(ws);                 // 3 x 589824 bf16 = 3,538,944 B
    u16* w1o     = (u16*)(ws + 3538944);       // 3 x  65536 bf16 =   393,216 B
    int* counts  = (int*)(ws + 3932160);       // 2 KB
    int* members = (int*)(ws + 3934208);       // 1 MB
    u16* bufA    = (u16*)(ws + 4982784);       // 51,380,224 B (bin -> fuse)
    u16* bufB    = (u16*)(ws + 56363008);      // 51,380,224 B (t1 -> t3); end 107,743,232

    wconv_kernel<<<960, 256, 0, stream>>>(Wc3, Wt3, Wf3, Wc1, Wt1, Wf1, w3, w1o);
    mask_kernel<<<512, 64, 0, stream>>>(boxes, counts, members);
    bin_kernel<<<512, 256, 0, stream>>>(x, cls, counts, members, bufA);
    // branch conv3x3 (per-class weights), bin -> t1
    conv3x3_kernel<<<1024, 256, 0, stream>>>(bufA, bufB, w3, w3 + 589824, cls, 1);
    // branch conv1x1 + (x + gc) fuse, t1 -> fuse
    conv1x1_kernel<0><<<1024, 256, 0, stream>>>(bufB, w1o, w1o + 65536, cls, 1, x, gc,
                                                nullptr, nullptr, nullptr, nullptr, (void*)bufA);
    // fuse conv3x3, fuse -> t3
    conv3x3_kernel<<<1024, 256, 0, stream>>>(bufA, bufB, w3 + 2 * 589824, w3, cls, 0);
    // final conv1x1 + BN + ReLU, t3 -> out (f32)
    conv1x1_kernel<1><<<1024, 256, 0, stream>>>(bufB, w1o + 2 * 65536, w1o, cls, 0, nullptr, nullptr,
                                                gam, bet, mea, var, (void*)out);
}

// Round 2
// 910.078 us; speedup vs baseline: 1.2581x; 1.2581x over previous
//
#include <hip/hip_runtime.h>

typedef unsigned short u16;
typedef unsigned int u32;
typedef __bf16 bf16x8 __attribute__((ext_vector_type(8)));
typedef float f32x4 __attribute__((ext_vector_type(4)));
typedef u16 u16x4 __attribute__((ext_vector_type(4)));
typedef float f4v __attribute__((ext_vector_type(4)));

#define NB   512
#define CCH  256
#define HW   196
#define LROW 40          // LDS row stride in bf16 elems
#define SSTR 53248       // per-sample elems in blocked layout: 64*208*4

__device__ inline u16 f2bf(float f) {
    u32 u = __float_as_uint(f);
    u32 r = (u + 0x7FFFu + ((u >> 16) & 1u)) >> 16;
    return (u16)r;
}

// ---------------- weight convert / reorder ----------------
__global__ void wconv_kernel(const float* __restrict__ Wc3, const float* __restrict__ Wt3,
                             const float* __restrict__ Wf3, const float* __restrict__ Wc1,
                             const float* __restrict__ Wt1, const float* __restrict__ Wf1,
                             u16* __restrict__ w3, u16* __restrict__ w1o)
{
    int bid = blockIdx.x, tid = threadIdx.x;
    if (bid < 768) {
        int wsel = bid >> 8;
        int co = bid & 255;
        const float* src = wsel == 0 ? Wc3 : (wsel == 1 ? Wt3 : Wf3);
#pragma unroll
        for (int rs = 0; rs < 9; ++rs) {
            float v = src[(co * 256 + tid) * 9 + rs];
            w3[wsel * 589824 + (rs * 256 + co) * 256 + tid] = f2bf(v);
        }
    } else {
        int k = (bid - 768) * 256 + tid;
        int wsel = k >> 14;
        int rem = k & 16383;
        const float* src = wsel == 0 ? Wc1 : (wsel == 1 ? Wt1 : Wf1);
        f4v v = *(const f4v*)(src + rem * 4);
        u16x4 o = { f2bf(v.x), f2bf(v.y), f2bf(v.z), f2bf(v.w) };
        *(u16x4*)(w1o + wsel * 65536 + rem * 4) = o;
    }
}

// ---------------- box overlap mask ----------------
__global__ void mask_kernel(const float* __restrict__ boxes, int* __restrict__ counts,
                            int* __restrict__ members)
{
    int i = blockIdx.x;
    int ln = threadIdx.x;
    __shared__ int cnt;
    if (ln == 0) cnt = 0;
    __syncthreads();
    float xi0 = boxes[i * 4 + 0], yi0 = boxes[i * 4 + 1];
    float xi1 = boxes[i * 4 + 2], yi1 = boxes[i * 4 + 3];
    for (int j = ln; j < NB; j += 64) {
        float xj0 = boxes[j * 4 + 0], yj0 = boxes[j * 4 + 1];
        float xj1 = boxes[j * 4 + 2], yj1 = boxes[j * 4 + 3];
        float areaj = (xj1 - xj0) * (yj1 - yj0);
        float lx = fmaxf(xi0, xj0), ly = fmaxf(yi0, yj0);
        float rx = fminf(xi1, xj1), ry = fminf(yi1, yj1);
        float w = fmaxf(rx - lx, 0.f), h = fmaxf(ry - ly, 0.f);
        if (w * h / areaj > 0.9f) {
            int p = atomicAdd(&cnt, 1);
            members[i * NB + p] = j;
        }
    }
    __syncthreads();
    if (ln == 0) counts[i] = cnt;
}

// ---------------- branch input -> blocked bf16 [s][c4][208][4] ----------------
__global__ void bin_kernel(const float* __restrict__ x, const int* __restrict__ classes,
                           const int* __restrict__ counts, const int* __restrict__ members,
                           u16* __restrict__ bin)
{
    const int s = blockIdx.x, tid = threadIdx.x;
    const int cnt = counts[s];
    u16* binS = bin + s * SSTR;
    if (classes[s] != 0 || cnt <= 1) {
        for (int v = tid; v < 64 * 208; v += 256) {
            int c4 = v / 208;
            int px = v - c4 * 208;
            u16x4 o = {0, 0, 0, 0};
            if (px < HW) {
#pragma unroll
                for (int rg = 0; rg < 4; ++rg)
                    o[rg] = f2bf(x[(s * CCH + c4 * 4 + rg) * HW + px]);
            }
            *(u16x4*)(binS + (c4 * 208 + px) * 4) = o;
        }
    } else {
        __shared__ int mem[NB];
        for (int u = tid; u < cnt; u += 256) mem[u] = members[s * NB + u];
        __syncthreads();
        const float inv = 1.f / (float)cnt;
        for (int v = tid; v < 64 * 208; v += 256) {
            int c4 = v / 208;
            int px = v - c4 * 208;
            u16x4 o = {0, 0, 0, 0};
            if (px < HW) {
                float a[4] = {0.f, 0.f, 0.f, 0.f};
                for (int k = 0; k < cnt; ++k) {
                    const float* xm = x + mem[k] * (CCH * HW);
#pragma unroll
                    for (int rg = 0; rg < 4; ++rg)
                        a[rg] += xm[(c4 * 4 + rg) * HW + px];
                }
#pragma unroll
                for (int rg = 0; rg < 4; ++rg) o[rg] = f2bf(a[rg] * inv);
            }
            *(u16x4*)(binS + (c4 * 208 + px) * 4) = o;
        }
    }
}

// ---------------- conv3x3: blocked in -> blocked out, 4 co-subtiles/wave ----------------
// grid 1024: s = bid>>1, t-half = bid&1. block 256 = 4 waves (co quarters of 64).
__global__ __launch_bounds__(256, 2) void conv3x3_kernel(
    const u16* __restrict__ in, u16* __restrict__ out,
    const u16* __restrict__ w0, const u16* __restrict__ w1,
    const int* __restrict__ classes, int useClass)
{
    __shared__ u16 lds[197 * LROW];
    const int tid = threadIdx.x;
    const int bid = blockIdx.x;
    const int s = bid >> 1;
    const int th = bid & 1;
    const int wv = tid >> 6;
    const int ln = tid & 63;
    const int q = ln >> 4;
    const int l15 = ln & 15;
    const int cobase = wv * 64;
    const int t0 = th * 7;
    const int NT = th ? 6 : 7;

    const u16* wsel = (useClass && classes[s] == 0) ? w1 : w0;

    if (tid < 20) ((u32*)lds)[196 * (LROW / 2) + tid] = 0u;

    int baddr[7], vbits[7];
#pragma unroll
    for (int t = 0; t < 7; ++t) {
        int tt = t0 + t;
        int px = tt * 16 + l15;
        int vb = 0;
        int ba = 196 * LROW + q * 8;
        if (t < NT && px < HW) {
            int y = px / 14;
            int x = px - y * 14;
            ba = px * LROW + q * 8;
#pragma unroll
            for (int rs = 0; rs < 9; ++rs) {
                int iy = y + rs / 3 - 1;
                int ix = x + rs % 3 - 1;
                if (iy >= 0 && iy < 14 && ix >= 0 && ix < 14) vb |= 1 << rs;
            }
        }
        baddr[t] = ba;
        vbits[t] = vb;
    }

    f32x4 acc[4][7];
#pragma unroll
    for (int a = 0; a < 4; ++a)
#pragma unroll
        for (int t = 0; t < 7; ++t) acc[a][t] = (f32x4){0.f, 0.f, 0.f, 0.f};

    const u16* inS = in + s * SSTR;

    for (int cc = 0; cc < 8; ++cc) {
        __syncthreads();
        for (int v = tid; v < 1568; v += 256) {       // 8 ci4 x 196 px
            int ci4 = v & 7;
            int px = v >> 3;
            u16x4 val = *(const u16x4*)(inS + ((cc * 8 + ci4) * 208 + px) * 4);
            *(u16x4*)(lds + px * LROW + ci4 * 4) = val;   // ds_write_b64, conflict-free
        }
        __syncthreads();

#pragma unroll
        for (int rs = 0; rs < 9; ++rs) {
            const int d = (rs / 3 - 1) * 14 + (rs % 3 - 1);
            bf16x8 af[4];
#pragma unroll
            for (int sub = 0; sub < 4; ++sub)
                af[sub] = *(const bf16x8*)(wsel + ((rs * 256 + cobase + sub * 16 + l15) * 256 + cc * 32 + q * 8));
#pragma unroll
            for (int t = 0; t < 7; ++t) {
                if (t < NT) {
                    int addr = ((vbits[t] >> rs) & 1) ? (baddr[t] + d * LROW)
                                                      : (196 * LROW + q * 8);
                    bf16x8 b = *(const bf16x8*)(lds + addr);
#pragma unroll
                    for (int sub = 0; sub < 4; ++sub)
                        acc[sub][t] = __builtin_amdgcn_mfma_f32_16x16x32_bf16(af[sub], b, acc[sub][t], 0, 0, 0);
                }
            }
        }
    }

    // blocked store: u16x4 per lane, fully coalesced
#pragma unroll
    for (int sub = 0; sub < 4; ++sub) {
        int co4 = (cobase >> 2) + sub * 4 + q;
#pragma unroll
        for (int t = 0; t < 7; ++t) {
            if (t < NT) {
                int pxs = (t0 + t) * 16 + l15;
                u16x4 o = { f2bf(acc[sub][t][0]), f2bf(acc[sub][t][1]),
                            f2bf(acc[sub][t][2]), f2bf(acc[sub][t][3]) };
                *(u16x4*)(out + (s * (size_t)SSTR) + (co4 * 208 + pxs) * 4) = o;
            }
        }
    }
}

// ---------------- conv1x1: blocked in, fused epilogues ----------------
// MODE 0: blocked bf16 out = acc + x + gc.  MODE 1: f32 NCHW out = relu(BN(acc)).
template <int MODE>
__global__ __launch_bounds__(256, 2) void conv1x1_kernel(
    const u16* __restrict__ in, const u16* __restrict__ w0, const u16* __restrict__ w1,
    const int* __restrict__ classes, int useClass,
    const float* __restrict__ xin, const float* __restrict__ gcin,
    const float* __restrict__ gamma, const float* __restrict__ beta,
    const float* __restrict__ mean, const float* __restrict__ var,
    void* __restrict__ outv)
{
    __shared__ u16 lds[197 * LROW];
    const int tid = threadIdx.x;
    const int bid = blockIdx.x;
    const int s = bid >> 1;
    const int th = bid & 1;
    const int wv = tid >> 6;
    const int ln = tid & 63;
    const int q = ln >> 4;
    const int l15 = ln & 15;
    const int cobase = wv * 64;
    const int t0 = th * 7;
    const int NT = th ? 6 : 7;

    const u16* wsel = (useClass && classes[s] == 0) ? w1 : w0;

    if (tid < 20) ((u32*)lds)[196 * (LROW / 2) + tid] = 0u;

    int baddr[7];
#pragma unroll
    for (int t = 0; t < 7; ++t) {
        int px = (t0 + t) * 16 + l15;
        baddr[t] = (t < NT && px < HW ? px : 196) * LROW + q * 8;
    }

    f32x4 acc[4][7];
#pragma unroll
    for (int a = 0; a < 4; ++a)
#pragma unroll
        for (int t = 0; t < 7; ++t) acc[a][t] = (f32x4){0.f, 0.f, 0.f, 0.f};

    const u16* inS = in + s * SSTR;

    for (int cc = 0; cc < 8; ++cc) {
        __syncthreads();
        for (int v = tid; v < 1568; v += 256) {
            int ci4 = v & 7;
            int px = v >> 3;
            u16x4 val = *(const u16x4*)(inS + ((cc * 8 + ci4) * 208 + px) * 4);
            *(u16x4*)(lds + px * LROW + ci4 * 4) = val;
        }
        __syncthreads();

        bf16x8 af[4];
#pragma unroll
        for (int sub = 0; sub < 4; ++sub)
            af[sub] = *(const bf16x8*)(wsel + ((cobase + sub * 16 + l15) * 256 + cc * 32 + q * 8));
#pragma unroll
        for (int t = 0; t < 7; ++t) {
            if (t < NT) {
                bf16x8 b = *(const bf16x8*)(lds + baddr[t]);
#pragma unroll
                for (int sub = 0; sub < 4; ++sub)
                    acc[sub][t] = __builtin_amdgcn_mfma_f32_16x16x32_bf16(af[sub], b, acc[sub][t], 0, 0, 0);
            }
        }
    }

    if (MODE == 0) {
        u16* outb = (u16*)outv;
#pragma unroll
        for (int sub = 0; sub < 4; ++sub) {
            int co4 = (cobase >> 2) + sub * 4 + q;
#pragma unroll
            for (int t = 0; t < 7; ++t) {
                if (t < NT) {
                    int pxs = (t0 + t) * 16 + l15;
                    u16x4 o = {0, 0, 0, 0};
                    if (pxs < HW) {
#pragma unroll
                        for (int rg = 0; rg < 4; ++rg) {
                            int idx = (s * CCH + co4 * 4 + rg) * HW + pxs;
                            o[rg] = f2bf(acc[sub][t][rg] + xin[idx] + gcin[idx]);
                        }
                    }
                    *(u16x4*)(outb + (s * (size_t)SSTR) + (co4 * 208 + pxs) * 4) = o;
                }
            }
        }
    } else {
        float* outf = (float*)outv;
        float scl[4][4], mn[4][4], bt[4][4];
#pragma unroll
        for (int sub = 0; sub < 4; ++sub)
#pragma unroll
            for (int rg = 0; rg < 4; ++rg) {
                int c = cobase + sub * 16 + q * 4 + rg;
                scl[sub][rg] = gamma[c] * rsqrtf(var[c] + 1e-5f);
                mn[sub][rg] = mean[c];
                bt[sub][rg] = beta[c];
            }
#pragma unroll
        for (int sub = 0; sub < 4; ++sub)
#pragma unroll
            for (int t = 0; t < 7; ++t) {
                if (t < NT) {
                    int pxs = (t0 + t) * 16 + l15;
                    if (pxs < HW) {
#pragma unroll
                        for (int rg = 0; rg < 4; ++rg) {
                            int co = cobase + sub * 16 + q * 4 + rg;
                            float v = (acc[sub][t][rg] - mn[sub][rg]) * scl[sub][rg] + bt[sub][rg];
                            outf[(s * CCH + co) * HW + pxs] = fmaxf(v, 0.f);
                        }
                    }
                }
            }
    }
}

// ---------------- launch ----------------
extern "C" void kernel_launch(void* const* d_in, const int* in_sizes, int n_in,
                              void* d_out, int out_size, void* d_ws, size_t ws_size,
                              hipStream_t stream)
{
    const float* x    = (const float*)d_in[0];
    const float* gc   = (const float*)d_in[1];
    const float* boxes= (const float*)d_in[2];
    const int*   cls  = (const int*)d_in[3];
    const float* Wc3  = (const float*)d_in[4];
    const float* Wc1  = (const float*)d_in[5];
    const float* Wt3  = (const float*)d_in[6];
    const float* Wt1  = (const float*)d_in[7];
    const float* Wf3  = (const float*)d_in[8];
    const float* Wf1  = (const float*)d_in[9];
    const float* gam  = (const float*)d_in[10];
    const float* bet  = (const float*)d_in[11];
    const float* mea  = (const float*)d_in[12];
    const float* var  = (const float*)d_in[13];
    float* out = (float*)d_out;
    char* ws = (char*)d_ws;

    u16* w3      = (u16*)(ws);                 // 3,538,944 B
    u16* w1o     = (u16*)(ws + 3538944);       //   393,216 B
    int* counts  = (int*)(ws + 3932160);
    int* members = (int*)(ws + 3934208);       // 1 MB
    u16* bufA    = (u16*)(ws + 4982784);       // 54,525,952 B  (bin -> fuse)
    u16* bufB    = (u16*)(ws + 59508736);      // 54,525,952 B  (t1 -> t3); end 114,034,688

    wconv_kernel<<<960, 256, 0, stream>>>(Wc3, Wt3, Wf3, Wc1, Wt1, Wf1, w3, w1o);
    mask_kernel<<<512, 64, 0, stream>>>(boxes, counts, members);
    bin_kernel<<<512, 256, 0, stream>>>(x, cls, counts, members, bufA);
    conv3x3_kernel<<<1024, 256, 0, stream>>>(bufA, bufB, w3, w3 + 589824, cls, 1);
    conv1x1_kernel<0><<<1024, 256, 0, stream>>>(bufB, w1o, w1o + 65536, cls, 1, x, gc,
                                                nullptr, nullptr, nullptr, nullptr, (void*)bufA);
    conv3x3_kernel<<<1024, 256, 0, stream>>>(bufA, bufB, w3 + 2 * 589824, w3, cls, 0);
    conv1x1_kernel<1><<<1024, 256, 0, stream>>>(bufB, w1o + 2 * 65536, w1o, cls, 0, nullptr, nullptr,
                                                gam, bet, mea, var, (void*)out);
}

// Round 3
// 872.414 us; speedup vs baseline: 1.3124x; 1.0432x over previous
//
#include <hip/hip_runtime.h>

typedef unsigned short u16;
typedef unsigned int u32;
typedef __bf16 bf16x8 __attribute__((ext_vector_type(8)));
typedef float f32x4 __attribute__((ext_vector_type(4)));
typedef u16 u16x4 __attribute__((ext_vector_type(4)));
typedef u16 u16x8 __attribute__((ext_vector_type(8)));
typedef float f4v __attribute__((ext_vector_type(4)));

#define NB   512
#define CCH  256
#define HW   196
#define LROW 40                    // act LDS row stride (elems)
#define ACT_ELEMS (197 * LROW)     // 7880 elems
#define WLDS_ELEMS (9 * 64 * 32)   // 18432 elems
#define SSTR 53248                 // per-sample elems, blocked [c4][208][4]
#define CGSTR 147456               // w3 per-co-group stride: 8cc*9rs*64co*32ci

__device__ inline u16 f2bf(float f) {
    u32 u = __float_as_uint(f);
    u32 r = (u + 0x7FFFu + ((u >> 16) & 1u)) >> 16;
    return (u16)r;
}

// ---------------- weight convert / reorder ----------------
// 3x3: W[co][ci][r][s] f32 -> w3[set][cg][cc][rs][co64][ci32] bf16
__global__ void wconv_kernel(const float* __restrict__ Wc3, const float* __restrict__ Wt3,
                             const float* __restrict__ Wf3, const float* __restrict__ Wc1,
                             const float* __restrict__ Wt1, const float* __restrict__ Wf1,
                             u16* __restrict__ w3, u16* __restrict__ w1o)
{
    int bid = blockIdx.x, tid = threadIdx.x;
    if (bid < 768) {
        int wset = bid >> 8;
        int co = bid & 255;
        int cgi = co >> 6, cop = co & 63;
        int cc = tid >> 5, cip = tid & 31;
        const float* src = wset == 0 ? Wc3 : (wset == 1 ? Wt3 : Wf3);
#pragma unroll
        for (int rs = 0; rs < 9; ++rs) {
            float v = src[(co * 256 + tid) * 9 + rs];
            w3[wset * 589824 + cgi * CGSTR + (cc * 9 + rs) * 2048 + cop * 32 + cip] = f2bf(v);
        }
    } else {
        int k = (bid - 768) * 256 + tid;
        int wsel = k >> 14;
        int rem = k & 16383;
        const float* src = wsel == 0 ? Wc1 : (wsel == 1 ? Wt1 : Wf1);
        f4v v = *(const f4v*)(src + rem * 4);
        u16x4 o = { f2bf(v.x), f2bf(v.y), f2bf(v.z), f2bf(v.w) };
        *(u16x4*)(w1o + wsel * 65536 + rem * 4) = o;
    }
}

// ---------------- box overlap mask ----------------
__global__ void mask_kernel(const float* __restrict__ boxes, int* __restrict__ counts,
                            int* __restrict__ members)
{
    int i = blockIdx.x;
    int ln = threadIdx.x;
    __shared__ int cnt;
    if (ln == 0) cnt = 0;
    __syncthreads();
    float xi0 = boxes[i * 4 + 0], yi0 = boxes[i * 4 + 1];
    float xi1 = boxes[i * 4 + 2], yi1 = boxes[i * 4 + 3];
    for (int j = ln; j < NB; j += 64) {
        float xj0 = boxes[j * 4 + 0], yj0 = boxes[j * 4 + 1];
        float xj1 = boxes[j * 4 + 2], yj1 = boxes[j * 4 + 3];
        float areaj = (xj1 - xj0) * (yj1 - yj0);
        float lx = fmaxf(xi0, xj0), ly = fmaxf(yi0, yj0);
        float rx = fminf(xi1, xj1), ry = fminf(yi1, yj1);
        float w = fmaxf(rx - lx, 0.f), h = fmaxf(ry - ly, 0.f);
        if (w * h / areaj > 0.9f) {
            int p = atomicAdd(&cnt, 1);
            members[i * NB + p] = j;
        }
    }
    __syncthreads();
    if (ln == 0) counts[i] = cnt;
}

// ---------------- branch input -> blocked bf16 [s][c4][208][4] ----------------
__global__ void bin_kernel(const float* __restrict__ x, const int* __restrict__ classes,
                           const int* __restrict__ counts, const int* __restrict__ members,
                           u16* __restrict__ bin)
{
    const int s = blockIdx.x, tid = threadIdx.x;
    const int cnt = counts[s];
    u16* binS = bin + s * SSTR;
    if (classes[s] != 0 || cnt <= 1) {
        for (int v = tid; v < 64 * 208; v += 256) {
            int c4 = v / 208;
            int px = v - c4 * 208;
            u16x4 o = {0, 0, 0, 0};
            if (px < HW) {
#pragma unroll
                for (int rg = 0; rg < 4; ++rg)
                    o[rg] = f2bf(x[(s * CCH + c4 * 4 + rg) * HW + px]);
            }
            *(u16x4*)(binS + (c4 * 208 + px) * 4) = o;
        }
    } else {
        __shared__ int mem[NB];
        for (int u = tid; u < cnt; u += 256) mem[u] = members[s * NB + u];
        __syncthreads();
        const float inv = 1.f / (float)cnt;
        for (int v = tid; v < 64 * 208; v += 256) {
            int c4 = v / 208;
            int px = v - c4 * 208;
            u16x4 o = {0, 0, 0, 0};
            if (px < HW) {
                float a[4] = {0.f, 0.f, 0.f, 0.f};
                for (int k = 0; k < cnt; ++k) {
                    const float* xm = x + mem[k] * (CCH * HW);
#pragma unroll
                    for (int rg = 0; rg < 4; ++rg)
                        a[rg] += xm[(c4 * 4 + rg) * HW + px];
                }
#pragma unroll
                for (int rg = 0; rg < 4; ++rg) o[rg] = f2bf(a[rg] * inv);
            }
            *(u16x4*)(binS + (c4 * 208 + px) * 4) = o;
        }
    }
}

// ---------------- conv3x3: LDS-staged weights + acts, 64co x 13t per block ----------------
// grid 2048: s = bid>>2, cg = bid&3 (64-co group). block 256 = 4 waves splitting
// px tiles {4,3,3,3}. acc[4][4] = 64 regs. Weights staged per cc (36.9 KB).
__global__ __launch_bounds__(256, 3) void conv3x3_kernel(
    const u16* __restrict__ in, u16* __restrict__ out,
    const u16* __restrict__ w0, const u16* __restrict__ w1,
    const int* __restrict__ classes, int useClass)
{
    __shared__ u16 lds[ACT_ELEMS + WLDS_ELEMS];   // 52,624 B -> 3 blocks/CU
    const int tid = threadIdx.x;
    const int bid = blockIdx.x;
    const int s  = bid >> 2;
    const int cg = bid & 3;
    const int wv = tid >> 6;
    const int ln = tid & 63;
    const int q = ln >> 4;
    const int l15 = ln & 15;
    const int t0 = (wv == 0) ? 0 : (wv == 1 ? 4 : (wv == 2 ? 7 : 10));
    const int NT = (wv == 0) ? 4 : 3;

    const u16* wsel = (((useClass && classes[s] == 0) ? w1 : w0)) + cg * CGSTR;

    if (tid < 20) ((u32*)lds)[196 * (LROW / 2) + tid] = 0u;   // zero halo row

    int baddr[4], vbits[4];
#pragma unroll
    for (int t = 0; t < 4; ++t) {
        int px = (t0 + t) * 16 + l15;
        int vb = 0;
        int ba = 196 * LROW + q * 8;
        if (t < NT && px < HW) {
            int y = px / 14;
            int x = px - y * 14;
            ba = px * LROW + q * 8;
#pragma unroll
            for (int rs = 0; rs < 9; ++rs) {
                int iy = y + rs / 3 - 1;
                int ix = x + rs % 3 - 1;
                if (iy >= 0 && iy < 14 && ix >= 0 && ix < 14) vb |= 1 << rs;
            }
        }
        baddr[t] = ba;
        vbits[t] = vb;
    }

    f32x4 acc[4][4];
#pragma unroll
    for (int a = 0; a < 4; ++a)
#pragma unroll
        for (int t = 0; t < 4; ++t) acc[a][t] = (f32x4){0.f, 0.f, 0.f, 0.f};

    const u16* inS = in + s * SSTR;

    for (int cc = 0; cc < 8; ++cc) {
        __syncthreads();
        // stage activations: 32 ci x 196 px, transposed to [px][ci32]
        for (int v = tid; v < 1568; v += 256) {
            int ci4 = v & 7;
            int px = v >> 3;
            u16x4 val = *(const u16x4*)(inS + ((cc * 8 + ci4) * 208 + px) * 4);
            *(u16x4*)(lds + px * LROW + ci4 * 4) = val;
        }
        // stage weights: 9rs x 64co x 32ci contiguous b128 copy
        {
            const u16* wcc = wsel + cc * WLDS_ELEMS;
#pragma unroll
            for (int k = 0; k < 9; ++k) {
                int idx = tid + k * 256;
                *(u16x8*)(lds + ACT_ELEMS + idx * 8) = *(const u16x8*)(wcc + idx * 8);
            }
        }
        __syncthreads();

#pragma unroll
        for (int rs = 0; rs < 9; ++rs) {
            const int d = (rs / 3 - 1) * 14 + (rs % 3 - 1);
            bf16x8 af[4];
#pragma unroll
            for (int sub = 0; sub < 4; ++sub)
                af[sub] = *(const bf16x8*)(lds + ACT_ELEMS + rs * 2048 + (sub * 16 + l15) * 32 + q * 8);
#pragma unroll
            for (int t = 0; t < 4; ++t) {
                if (t < NT) {
                    int addr = ((vbits[t] >> rs) & 1) ? (baddr[t] + d * LROW)
                                                      : (196 * LROW + q * 8);
                    bf16x8 b = *(const bf16x8*)(lds + addr);
#pragma unroll
                    for (int sub = 0; sub < 4; ++sub)
                        acc[sub][t] = __builtin_amdgcn_mfma_f32_16x16x32_bf16(af[sub], b, acc[sub][t], 0, 0, 0);
                }
            }
        }
    }

#pragma unroll
    for (int sub = 0; sub < 4; ++sub) {
        int co4 = cg * 16 + sub * 4 + q;
#pragma unroll
        for (int t = 0; t < 4; ++t) {
            if (t < NT) {
                int pxs = (t0 + t) * 16 + l15;
                u16x4 o = { f2bf(acc[sub][t][0]), f2bf(acc[sub][t][1]),
                            f2bf(acc[sub][t][2]), f2bf(acc[sub][t][3]) };
                *(u16x4*)(out + (s * (size_t)SSTR) + (co4 * 208 + pxs) * 4) = o;
            }
        }
    }
}

// ---------------- conv1x1: retiled 64co x 13t per block, fused epilogues ----------------
template <int MODE>
__global__ __launch_bounds__(256, 3) void conv1x1_kernel(
    const u16* __restrict__ in, const u16* __restrict__ w0, const u16* __restrict__ w1,
    const int* __restrict__ classes, int useClass,
    const float* __restrict__ xin, const float* __restrict__ gcin,
    const float* __restrict__ gamma, const float* __restrict__ beta,
    const float* __restrict__ mean, const float* __restrict__ var,
    void* __restrict__ outv)
{
    __shared__ u16 lds[ACT_ELEMS];
    const int tid = threadIdx.x;
    const int bid = blockIdx.x;
    const int s  = bid >> 2;
    const int cg = bid & 3;
    const int wv = tid >> 6;
    const int ln = tid & 63;
    const int q = ln >> 4;
    const int l15 = ln & 15;
    const int t0 = (wv == 0) ? 0 : (wv == 1 ? 4 : (wv == 2 ? 7 : 10));
    const int NT = (wv == 0) ? 4 : 3;

    const u16* wsel = (useClass && classes[s] == 0) ? w1 : w0;

    if (tid < 20) ((u32*)lds)[196 * (LROW / 2) + tid] = 0u;

    int baddr[4];
#pragma unroll
    for (int t = 0; t < 4; ++t) {
        int px = (t0 + t) * 16 + l15;
        baddr[t] = (t < NT && px < HW ? px : 196) * LROW + q * 8;
    }

    f32x4 acc[4][4];
#pragma unroll
    for (int a = 0; a < 4; ++a)
#pragma unroll
        for (int t = 0; t < 4; ++t) acc[a][t] = (f32x4){0.f, 0.f, 0.f, 0.f};

    const u16* inS = in + s * SSTR;

    for (int cc = 0; cc < 8; ++cc) {
        __syncthreads();
        for (int v = tid; v < 1568; v += 256) {
            int ci4 = v & 7;
            int px = v >> 3;
            u16x4 val = *(const u16x4*)(inS + ((cc * 8 + ci4) * 208 + px) * 4);
            *(u16x4*)(lds + px * LROW + ci4 * 4) = val;
        }
        __syncthreads();

        bf16x8 af[4];
#pragma unroll
        for (int sub = 0; sub < 4; ++sub)
            af[sub] = *(const bf16x8*)(wsel + ((cg * 64 + sub * 16 + l15) * 256 + cc * 32 + q * 8));
#pragma unroll
        for (int t = 0; t < 4; ++t) {
            if (t < NT) {
                bf16x8 b = *(const bf16x8*)(lds + baddr[t]);
#pragma unroll
                for (int sub = 0; sub < 4; ++sub)
                    acc[sub][t] = __builtin_amdgcn_mfma_f32_16x16x32_bf16(af[sub], b, acc[sub][t], 0, 0, 0);
            }
        }
    }

    if (MODE == 0) {
        u16* outb = (u16*)outv;
#pragma unroll
        for (int sub = 0; sub < 4; ++sub) {
            int co4 = cg * 16 + sub * 4 + q;
#pragma unroll
            for (int t = 0; t < 4; ++t) {
                if (t < NT) {
                    int pxs = (t0 + t) * 16 + l15;
                    u16x4 o = {0, 0, 0, 0};
                    if (pxs < HW) {
#pragma unroll
                        for (int rg = 0; rg < 4; ++rg) {
                            int idx = (s * CCH + co4 * 4 + rg) * HW + pxs;
                            o[rg] = f2bf(acc[sub][t][rg] + xin[idx] + gcin[idx]);
                        }
                    }
                    *(u16x4*)(outb + (s * (size_t)SSTR) + (co4 * 208 + pxs) * 4) = o;
                }
            }
        }
    } else {
        float* outf = (float*)outv;
        float scl[4][4], mn[4][4], bt[4][4];
#pragma unroll
        for (int sub = 0; sub < 4; ++sub)
#pragma unroll
            for (int rg = 0; rg < 4; ++rg) {
                int c = cg * 64 + sub * 16 + q * 4 + rg;
                scl[sub][rg] = gamma[c] * rsqrtf(var[c] + 1e-5f);
                mn[sub][rg] = mean[c];
                bt[sub][rg] = beta[c];
            }
#pragma unroll
        for (int sub = 0; sub < 4; ++sub)
#pragma unroll
            for (int t = 0; t < 4; ++t) {
                if (t < NT) {
                    int pxs = (t0 + t) * 16 + l15;
                    if (pxs < HW) {
#pragma unroll
                        for (int rg = 0; rg < 4; ++rg) {
                            int co = cg * 64 + sub * 16 + q * 4 + rg;
                            float v = (acc[sub][t][rg] - mn[sub][rg]) * scl[sub][rg] + bt[sub][rg];
                            outf[(s * CCH + co) * HW + pxs] = fmaxf(v, 0.f);
                        }
                    }
                }
            }
    }
}

// ---------------- launch ----------------
extern "C" void kernel_launch(void* const* d_in, const int* in_sizes, int n_in,
                              void* d_out, int out_size, void* d_ws, size_t ws_size,
                              hipStream_t stream)
{
    const float* x    = (const float*)d_in[0];
    const float* gc   = (const float*)d_in[1];
    const float* boxes= (const float*)d_in[2];
    const int*   cls  = (const int*)d_in[3];
    const float* Wc3  = (const float*)d_in[4];
    const float* Wc1  = (const float*)d_in[5];
    const float* Wt3  = (const float*)d_in[6];
    const float* Wt1  = (const float*)d_in[7];
    const float* Wf3  = (const float*)d_in[8];
    const float* Wf1  = (const float*)d_in[9];
    const float* gam  = (const float*)d_in[10];
    const float* bet  = (const float*)d_in[11];
    const float* mea  = (const float*)d_in[12];
    const float* var  = (const float*)d_in[13];
    float* out = (float*)d_out;
    char* ws = (char*)d_ws;

    u16* w3      = (u16*)(ws);                 // 3,538,944 B
    u16* w1o     = (u16*)(ws + 3538944);       //   393,216 B
    int* counts  = (int*)(ws + 3932160);
    int* members = (int*)(ws + 3934208);       // 1 MB
    u16* bufA    = (u16*)(ws + 4982784);       // 54,525,952 B
    u16* bufB    = (u16*)(ws + 59508736);      // 54,525,952 B; end 114,034,688

    wconv_kernel<<<960, 256, 0, stream>>>(Wc3, Wt3, Wf3, Wc1, Wt1, Wf1, w3, w1o);
    mask_kernel<<<512, 64, 0, stream>>>(boxes, counts, members);
    bin_kernel<<<512, 256, 0, stream>>>(x, cls, counts, members, bufA);
    conv3x3_kernel<<<2048, 256, 0, stream>>>(bufA, bufB, w3, w3 + 589824, cls, 1);
    conv1x1_kernel<0><<<2048, 256, 0, stream>>>(bufB, w1o, w1o + 65536, cls, 1, x, gc,
                                                nullptr, nullptr, nullptr, nullptr, (void*)bufA);
    conv3x3_kernel<<<2048, 256, 0, stream>>>(bufA, bufB, w3 + 2 * 589824, w3, cls, 0);
    conv1x1_kernel<1><<<2048, 256, 0, stream>>>(bufB, w1o + 2 * 65536, w1o, cls, 0, nullptr, nullptr,
                                                gam, bet, mea, var, (void*)out);
}